// Round 1
// baseline (79.097 us; speedup 1.0000x reference)
//
#include <hip/hip_runtime.h>
#include <math.h>

#define N      1000           // NCLASSES
#define K      5
#define NTH1   512            // K1: 8 waves; wave w owns positions [128w,128w+128)
#define NTH2   256            // K2: 64 j-lanes x 4 k-quarters
#define MSLICE 16             // K2 blocks per row
#define SROW   1008           // ws row stride (floats); S[0..1000] only (guarded)
#define META   (64 * SROW)    // float offset of metadata
// meta layout (floats/uints at ws + META + ...):
//   [+0   + r] int p          [+64  + r] float tval
//   [+128 + r] unsigned mr    [+192 + r] unsigned loss bits
//   [+256 + r] unsigned tick  [+320]     unsigned gdone
//
// R9: K3 folded into K2 via a two-level relaxed-ticket tail.
//   - R8 lesson: 1024 device fences + one same-address done-counter = +9us.
//   - Here: NO fences. All cross-block state is atomic-RMW-only (device scope
//     = coherent point), so ordering needs only a same-thread
//     s_waitcnt vmcnt(0) between "my atomicMin performed" and "my ticket-add
//     performed". Tickets spread over 64 addresses (16 adds each).
//   - Row finisher (ticket==15) computes loss_r; global finisher (gdone==63)
//     reads 64 loss slots via identity-RMW and reduces in EXACTLY k3's shfl
//     tree order (off=32..1, static unroll) -> bit-identical result.

// ---- order-preserving float<->uint for atomicMin ----
__device__ inline unsigned fkey(float x) {
    unsigned u = __float_as_uint(x);
    return (u & 0x80000000u) ? ~u : (u | 0x80000000u);
}
__device__ inline float fdecode(unsigned u) {
    return __uint_as_float((u & 0x80000000u) ? (u & 0x7FFFFFFFu) : ~u);
}

// ===================== K1: sort + prefix-scan + rank ========================
__global__ __launch_bounds__(NTH1) void k1_sort_scan(
    const float* __restrict__ mat, const int* __restrict__ target,
    float* __restrict__ ws)
{
    __shared__ float sx[2][1024];    // double-buffered exchange: 1 barrier/stage
    __shared__ float wtot[8];
    __shared__ int   cnt_sh;

    const int tid  = threadIdx.x;
    const int lane = tid & 63;
    const int w    = tid >> 6;
    const int i0   = (w << 7) + lane;
    const int i1   = i0 + 64;
    const int r    = blockIdx.x;
    const float* row = mat + r * N;
    const int   tgt  = target[r];
    const float tval = row[tgt];

    float r0 = row[i0];                          // i0 <= 959 < N
    float r1 = (i1 < N) ? row[i1] : -INFINITY;
    if (tid == 0) cnt_sh = 0;

    // stable descending-sort position of the target
    int lc = ((r0 > tval) || (r0 == tval && i0 < tgt))
           + ((r1 > tval) || (r1 == tval && i1 < tgt));
    #pragma unroll
    for (int off = 32; off; off >>= 1) lc += __shfl_down(lc, off);
    __syncthreads();                             // cnt_sh=0 visible
    if (lane == 0 && lc) atomicAdd(&cnt_sh, lc);

    // bitonic sort, descending (shuffle j<=32, register j=64, LDS j>=128)
    auto cas_shfl = [&](float& rr, int i, unsigned k, unsigned j) {
        float o = __shfl_xor(rr, (int)j);
        bool lower = ((lane & (int)j) == 0);
        bool desc  = ((i & (int)k) == 0);
        rr = (lower == desc) ? fmaxf(rr, o) : fminf(rr, o);
    };
    #pragma unroll
    for (unsigned k = 2; k <= 64; k <<= 1)
        #pragma unroll
        for (unsigned j = k >> 1; j; j >>= 1) { cas_shfl(r0, i0, k, j); cas_shfl(r1, i1, k, j); }
    int buf = 0;
    #pragma unroll
    for (unsigned k = 128; k <= 1024; k <<= 1) {
        #pragma unroll
        for (unsigned j = k >> 1; j >= 128; j >>= 1) {
            // double-buffer: stage-s reads of buf retire (lgkmcnt in barrier)
            // before any wave passes stage-(s+1)'s barrier to rewrite it
            sx[buf][i0] = r0; sx[buf][i1] = r1;
            __syncthreads();
            float o0 = sx[buf][i0 ^ (int)j], o1 = sx[buf][i1 ^ (int)j];
            buf ^= 1;
            bool lower = ((i0 & (int)j) == 0);   // same for i1 (j>=128)
            bool desc  = ((i0 & (int)k) == 0);   // same for i1 (k>=256)
            r0 = (lower == desc) ? fmaxf(r0, o0) : fminf(r0, o0);
            r1 = (lower == desc) ? fmaxf(r1, o1) : fminf(r1, o1);
        }
        {   // j == 64: in-lane register swap
            bool desc = ((i0 & (int)k) == 0);
            float a = fmaxf(r0, r1), b = fminf(r0, r1);
            r0 = desc ? a : b;
            r1 = desc ? b : a;
        }
        #pragma unroll
        for (unsigned j = 32; j; j >>= 1) { cas_shfl(r0, i0, k, j); cas_shfl(r1, i1, k, j); }
    }

    // prefix sums (shuffle scans); -inf pads -> 0
    if (i1 >= N) r1 = 0.0f;
    float incl0 = r0;
    #pragma unroll
    for (int off = 1; off < 64; off <<= 1) {
        float y = __shfl_up(incl0, off);
        if (lane >= off) incl0 += y;
    }
    float tot0 = __shfl(incl0, 63);
    float incl1 = r1;
    #pragma unroll
    for (int off = 1; off < 64; off <<= 1) {
        float y = __shfl_up(incl1, off);
        if (lane >= off) incl1 += y;
    }
    if (lane == 63) wtot[w] = incl0 + incl1;
    __syncthreads();
    float base = 0.0f;
    #pragma unroll
    for (int u = 0; u < 8; ++u) { float t = wtot[u]; if (u < w) base += t; }

    float* Sg = ws + r * SROW;
    if (tid == 0) Sg[0] = 0.0f;
    Sg[i0 + 1] = base + incl0;                   // i0+1 <= 960 < SROW
    if (i1 < N) Sg[i1 + 1] = base + tot0 + incl1;   // only S[1..1000]
    if (tid == 0) {
        ((int*)ws)[META + r]            = cnt_sh;        // p
        ws[META + 64 + r]               = tval;
        ((unsigned*)ws)[META + 128 + r] = 0xFFFFFFFFu;   // mr sentinel (+max key)
        ((unsigned*)ws)[META + 256 + r] = 0u;            // per-row ticket
        if (r == 0) ((unsigned*)ws)[META + 320] = 0u;    // global row-done counter
    }
}

// ============ K2: min-max at position p + fused loss tail ===================
__global__ __launch_bounds__(NTH2, 4) void k2_minmax(
    float* __restrict__ ws, float* __restrict__ out)
{
    __shared__ float Sloc[N];    // S[p+1 .. N]
    __shared__ float rtab[N];    // 1/(d+1)
    __shared__ float maxh[NTH2];

    const int r  = blockIdx.y;
    const int m  = blockIdx.x;
    const int t  = threadIdx.x;
    const int p  = ((const int*)ws)[META + r];
    const int j0 = m * 64;
    unsigned* __restrict__ mrg   = (unsigned*)(ws + META + 128);
    unsigned* __restrict__ lossu = (unsigned*)(ws + META + 192);
    unsigned* __restrict__ tick  = (unsigned*)(ws + META + 256);
    unsigned* __restrict__ gdone = (unsigned*)(ws + META + 320);
    const float* __restrict__ tvg = ws + META + 64;

    if (j0 <= p) {                               // active slice: do the work
        const int len = N - p;
        const float* Srow = ws + r * SROW;

        const int jl = t & 63;
        const int j  = j0 + jl;
        const float Sj = (j <= p) ? Srow[j] : 0.0f;   // hoisted global load

        for (int i = t; i < len; i += NTH2) Sloc[i] = Srow[p + 1 + i];
        for (int d = t; d < N; d += NTH2) rtab[d] = 1.0f / (float)(d + 1);
        __syncthreads();

        const int q  = t >> 6;                 // wave-uniform k-quarter
        const int k0 = (q * len) >> 2;
        const int k1 = ((q + 1) * len) >> 2;
        float maxv = -INFINITY;
        if (j <= p) {
            const float* sp = &Sloc[k0];       // wave-uniform addr -> broadcast
            const float* rp = &rtab[p + k0 - j];  // stride-1 across lanes
            float c = 0.5f * (float)(j + p + k0) - (float)N;  // (j+k)/2 - N
            #pragma unroll 8
            for (int it = 0; it < k1 - k0; ++it) {
                float mval = fmaf(sp[it] - Sj, rp[it], c);
                maxv = fmaxf(maxv, mval);
                c += 0.5f;                     // exact (multiples of 0.5)
            }
        }
        maxh[t] = maxv;
        __syncthreads();
        if (t < 64) {                          // combine quarters + min-reduce
            float mv = fmaxf(fmaxf(maxh[t], maxh[t + 64]),
                             fmaxf(maxh[t + 128], maxh[t + 192]));
            float minv = (j0 + t <= p) ? mv : INFINITY;
            #pragma unroll
            for (int off = 32; off; off >>= 1)
                minv = fminf(minv, __shfl_down(minv, off));
            if (t == 0) atomicMin(&mrg[r], fkey(minv));
        }
    }

    // ---- ticket tail (every slice, active or not; t==0 only) ----
    if (t == 0) {
        // order: my atomicMin (if any) performed BEFORE my ticket-add performs.
        // Both are device-scope RMWs at the coherent point; same-thread
        // ordering needs only the ack wait -- no cache fences.
        asm volatile("s_waitcnt vmcnt(0)" ::: "memory");
        unsigned prev = atomicAdd(&tick[r], 1u);
        if (prev == MSLICE - 1) {              // row finisher: all 16 slices done
            unsigned key = atomicMin(&mrg[r], 0xFFFFFFFFu);  // identity RMW read
            float sol  = fdecode(key);
            float rank = tvg[r] - sol;         // plain read: K1 data, boundary-visible
            float loss = fmaxf(0.0f, (float)(N - K + 1) - rank);
            atomicExch(&lossu[r], __float_as_uint(loss));
            asm volatile("s_waitcnt vmcnt(0)" ::: "memory");
            unsigned g = atomicAdd(gdone, 1u);
            if (g == 63u) {                    // global finisher: all rows done
                float v[64];
                #pragma unroll
                for (int i = 0; i < 64; ++i)
                    v[i] = __uint_as_float(atomicAdd(&lossu[i], 0u));  // RMW read
                // exact k3 shfl-tree association (off = 32,16,8,4,2,1)
                #pragma unroll
                for (int off = 32; off; off >>= 1)
                    #pragma unroll
                    for (int i = 0; i < off; ++i) v[i] += v[i + off];
                out[0] = v[0] * (1.0f / 64.0f);   // pow2 scale == /64 bitwise
            }
        }
    }
}

// ===================== fallback: monolithic (R4) ============================
__global__ __launch_bounds__(NTH1) void topk_loss_mono(
    const float* __restrict__ mat, const int* __restrict__ target,
    float* __restrict__ d_out, int nrows)
{
    __shared__ float S[1025];
    __shared__ float rcp[N];
    __shared__ float sx[1024];
    __shared__ float wtot[8];
    __shared__ float red[8];
    __shared__ int   cnt_sh;

    const int tid  = threadIdx.x;
    const int lane = tid & 63;
    const int w    = tid >> 6;
    const int i0   = (w << 7) + lane;
    const int i1   = i0 + 64;
    const float* row = mat + blockIdx.x * N;
    const int   tgt  = target[blockIdx.x];
    const float tval = row[tgt];

    float r0 = row[i0];
    float r1 = (i1 < N) ? row[i1] : -INFINITY;
    if (tid == 0) cnt_sh = 0;
    rcp[tid] = 1.0f / (float)(tid + 1);
    if (tid + NTH1 < N) rcp[tid + NTH1] = 1.0f / (float)(tid + NTH1 + 1);

    int lc = ((r0 > tval) || (r0 == tval && i0 < tgt))
           + ((r1 > tval) || (r1 == tval && i1 < tgt));
    #pragma unroll
    for (int off = 32; off; off >>= 1) lc += __shfl_down(lc, off);
    __syncthreads();
    if (lane == 0 && lc) atomicAdd(&cnt_sh, lc);

    auto cas_shfl = [&](float& rr, int i, unsigned k, unsigned j) {
        float o = __shfl_xor(rr, (int)j);
        bool lower = ((lane & (int)j) == 0);
        bool desc  = ((i & (int)k) == 0);
        rr = (lower == desc) ? fmaxf(rr, o) : fminf(rr, o);
    };
    #pragma unroll
    for (unsigned k = 2; k <= 64; k <<= 1)
        #pragma unroll
        for (unsigned j = k >> 1; j; j >>= 1) { cas_shfl(r0, i0, k, j); cas_shfl(r1, i1, k, j); }
    #pragma unroll
    for (unsigned k = 128; k <= 1024; k <<= 1) {
        #pragma unroll
        for (unsigned j = k >> 1; j >= 128; j >>= 1) {
            __syncthreads();
            sx[i0] = r0; sx[i1] = r1;
            __syncthreads();
            float o0 = sx[i0 ^ (int)j], o1 = sx[i1 ^ (int)j];
            bool lower = ((i0 & (int)j) == 0);
            bool desc  = ((i0 & (int)k) == 0);
            r0 = (lower == desc) ? fmaxf(r0, o0) : fminf(r0, o0);
            r1 = (lower == desc) ? fmaxf(r1, o1) : fminf(r1, o1);
        }
        {
            bool desc = ((i0 & (int)k) == 0);
            float a = fmaxf(r0, r1), b = fminf(r0, r1);
            r0 = desc ? a : b;
            r1 = desc ? b : a;
        }
        #pragma unroll
        for (unsigned j = 32; j; j >>= 1) { cas_shfl(r0, i0, k, j); cas_shfl(r1, i1, k, j); }
    }

    if (i1 >= N) r1 = 0.0f;
    float incl0 = r0;
    #pragma unroll
    for (int off = 1; off < 64; off <<= 1) {
        float y = __shfl_up(incl0, off);
        if (lane >= off) incl0 += y;
    }
    float tot0 = __shfl(incl0, 63);
    float incl1 = r1;
    #pragma unroll
    for (int off = 1; off < 64; off <<= 1) {
        float y = __shfl_up(incl1, off);
        if (lane >= off) incl1 += y;
    }
    if (lane == 63) wtot[w] = incl0 + incl1;
    __syncthreads();
    float base = 0.0f;
    #pragma unroll
    for (int u = 0; u < 8; ++u) { float t = wtot[u]; if (u < w) base += t; }
    if (tid == 0) S[0] = 0.0f;
    S[i0 + 1] = base + incl0;
    S[i1 + 1] = base + tot0 + incl1;
    __syncthreads();

    const int p   = cnt_sh;
    const int len = N - p;
    float minv = INFINITY;
    for (int j = tid; j <= p; j += NTH1) {
        const float  Sj = S[j];
        const float* Sp = &S[p + 1];
        const float* rp = &rcp[p - j];
        const float  cj = 0.5f * (float)(j + p) - (float)N;
        float maxv = -INFINITY;
        #pragma unroll 8
        for (int it = 0; it < len; ++it) {
            float mm = fmaf(Sp[it] - Sj, rp[it], cj + 0.5f * (float)it);
            maxv = fmaxf(maxv, mm);
        }
        minv = fminf(minv, maxv);
    }
    #pragma unroll
    for (int off = 32; off; off >>= 1) minv = fminf(minv, __shfl_down(minv, off));
    if (lane == 0) red[w] = minv;
    __syncthreads();
    if (tid == 0) {
        float sol = red[0];
        #pragma unroll
        for (int u = 1; u < 8; ++u) sol = fminf(sol, red[u]);
        float rank_label = tval - sol;
        float loss = fmaxf(0.0f, (float)(N - 5 + 1) - rank_label);
        atomicAdd(d_out, loss / (float)nrows);
    }
}

extern "C" void kernel_launch(void* const* d_in, const int* in_sizes, int n_in,
                              void* d_out, int out_size, void* d_ws, size_t ws_size,
                              hipStream_t stream) {
    (void)n_in;
    const float* mat    = (const float*)d_in[0];
    const int*   target = (const int*)d_in[1];
    float*       out    = (float*)d_out;
    const int    nrows  = in_sizes[1];   // 64

    const size_t need = (size_t)(META + 324) * sizeof(float);
    if (nrows == 64 && ws_size >= need) {
        float* ws = (float*)d_ws;
        k1_sort_scan<<<nrows, NTH1, 0, stream>>>(mat, target, ws);
        dim3 g2(MSLICE, nrows);
        k2_minmax<<<g2, NTH2, 0, stream>>>(ws, out);
    } else {
        hipMemsetAsync(out, 0, sizeof(float) * out_size, stream);
        topk_loss_mono<<<nrows, NTH1, 0, stream>>>(mat, target, out, nrows);
    }
}

// Round 2
// 72.773 us; speedup vs baseline: 1.0869x; 1.0869x over previous
//
#include <hip/hip_runtime.h>
#include <math.h>

#define N      1000           // NCLASSES
#define K      5
#define NTH1   512            // fused kernel: 8 waves; wave w owns [128w,128w+128)
// R10: K2 folded INTO K1 (not via atomics -- via LDS locality). S never leaves
// LDS; per-row block does sort -> scan -> min-max -> one loss[r] store.
// 3 dispatches -> 2. R9 lesson (reverted): in-kernel completion protocols cost
// ~+10us; kernel boundaries are the cheap visibility mechanism.
// ws layout: ws[0..63] = per-row loss (floats). Nothing else.

// ============== K1': sort + prefix-scan + isotonic min-max ==================
__global__ __launch_bounds__(NTH1) void k1_fused(
    const float* __restrict__ mat, const int* __restrict__ target,
    float* __restrict__ lossw)
{
    __shared__ float sx[2][1024];    // double-buffered bitonic exchange
    __shared__ float S[1025];        // prefix sums S[0..1000]
    __shared__ float rtab[N];        // 1/(d+1)
    __shared__ float pm[8][16][64];  // [k-octant][j-block][j-lane] partial max
    __shared__ float wtot[8];
    __shared__ float redm[8];
    __shared__ int   cnt_sh;

    const int tid  = threadIdx.x;
    const int lane = tid & 63;
    const int w    = tid >> 6;
    const int i0   = (w << 7) + lane;
    const int i1   = i0 + 64;
    const int r    = blockIdx.x;
    const float* row = mat + r * N;
    const int   tgt  = target[r];
    const float tval = row[tgt];

    float r0 = row[i0];                          // i0 <= 959 < N
    float r1 = (i1 < N) ? row[i1] : -INFINITY;
    if (tid == 0) cnt_sh = 0;
    rtab[tid] = 1.0f / (float)(tid + 1);         // filled long before use
    if (tid + NTH1 < N) rtab[tid + NTH1] = 1.0f / (float)(tid + NTH1 + 1);

    // stable descending-sort position of the target
    int lc = ((r0 > tval) || (r0 == tval && i0 < tgt))
           + ((r1 > tval) || (r1 == tval && i1 < tgt));
    #pragma unroll
    for (int off = 32; off; off >>= 1) lc += __shfl_down(lc, off);
    __syncthreads();                             // cnt_sh=0 (and rtab) visible
    if (lane == 0 && lc) atomicAdd(&cnt_sh, lc);

    // bitonic sort, descending (shuffle j<=32, register j=64, LDS j>=128)
    auto cas_shfl = [&](float& rr, int i, unsigned k, unsigned j) {
        float o = __shfl_xor(rr, (int)j);
        bool lower = ((lane & (int)j) == 0);
        bool desc  = ((i & (int)k) == 0);
        rr = (lower == desc) ? fmaxf(rr, o) : fminf(rr, o);
    };
    #pragma unroll
    for (unsigned k = 2; k <= 64; k <<= 1)
        #pragma unroll
        for (unsigned j = k >> 1; j; j >>= 1) { cas_shfl(r0, i0, k, j); cas_shfl(r1, i1, k, j); }
    int buf = 0;
    #pragma unroll
    for (unsigned k = 128; k <= 1024; k <<= 1) {
        #pragma unroll
        for (unsigned j = k >> 1; j >= 128; j >>= 1) {
            // double-buffer: stage-s reads of buf retire (lgkmcnt in barrier)
            // before any wave passes stage-(s+1)'s barrier to rewrite it
            sx[buf][i0] = r0; sx[buf][i1] = r1;
            __syncthreads();
            float o0 = sx[buf][i0 ^ (int)j], o1 = sx[buf][i1 ^ (int)j];
            buf ^= 1;
            bool lower = ((i0 & (int)j) == 0);   // same for i1 (j>=128)
            bool desc  = ((i0 & (int)k) == 0);   // same for i1 (k>=256)
            r0 = (lower == desc) ? fmaxf(r0, o0) : fminf(r0, o0);
            r1 = (lower == desc) ? fmaxf(r1, o1) : fminf(r1, o1);
        }
        {   // j == 64: in-lane register swap
            bool desc = ((i0 & (int)k) == 0);
            float a = fmaxf(r0, r1), b = fminf(r0, r1);
            r0 = desc ? a : b;
            r1 = desc ? b : a;
        }
        #pragma unroll
        for (unsigned j = 32; j; j >>= 1) { cas_shfl(r0, i0, k, j); cas_shfl(r1, i1, k, j); }
    }

    // prefix sums (shuffle scans); -inf pads -> 0
    if (i1 >= N) r1 = 0.0f;
    float incl0 = r0;
    #pragma unroll
    for (int off = 1; off < 64; off <<= 1) {
        float y = __shfl_up(incl0, off);
        if (lane >= off) incl0 += y;
    }
    float tot0 = __shfl(incl0, 63);
    float incl1 = r1;
    #pragma unroll
    for (int off = 1; off < 64; off <<= 1) {
        float y = __shfl_up(incl1, off);
        if (lane >= off) incl1 += y;
    }
    if (lane == 63) wtot[w] = incl0 + incl1;
    __syncthreads();
    float base = 0.0f;
    #pragma unroll
    for (int u = 0; u < 8; ++u) { float t = wtot[u]; if (u < w) base += t; }

    if (tid == 0) S[0] = 0.0f;
    S[i0 + 1] = base + incl0;
    if (i1 < N) S[i1 + 1] = base + tot0 + incl1;    // only S[1..1000]
    __syncthreads();                                 // S, cnt_sh final

    // ---- min-max at position p: sol = min_{j<=p} max_{k>=p} mean(y[j..k]) ----
    // mean = (S[k+1]-S[j])*rcp[k-j] + (j+k)/2 - N ; 64 j-lanes x 8 k-octants.
    const int p   = cnt_sh;
    const int len = N - p;
    const int k0q = (w * len) >> 3;                  // wave-uniform octant
    const int k1q = ((w + 1) * len) >> 3;
    const float* sp = &S[p + 1 + k0q];               // wave-uniform -> broadcast
    float pmax[16];
    #pragma unroll
    for (int jb = 0; jb < 16; ++jb) {                // static idx (rule #20)
        float mv = -INFINITY;
        const int j = (jb << 6) + lane;
        if ((jb << 6) <= p && j <= p) {              // block-uniform + lane guard
            const float  Sj = S[j];
            const float* rp = &rtab[p + k0q - j];    // stride-1 across lanes
            float c = 0.5f * (float)(j + p + k0q) - (float)N;  // (j+k)/2 - N
            #pragma unroll 8
            for (int it = 0; it < k1q - k0q; ++it) {
                mv = fmaxf(mv, fmaf(sp[it] - Sj, rp[it], c));
                c += 0.5f;                           // exact (multiples of 0.5)
            }
        }
        pm[w][jb][lane] = mv;
    }
    __syncthreads();

    // combine octants (max is exact -> regrouping is bitwise-safe), min over j
    auto comb = [&](int jb) -> float {
        float m = pm[0][jb][lane];
        #pragma unroll
        for (int o = 1; o < 8; ++o) m = fmaxf(m, pm[o][jb][lane]);
        return (((jb << 6) + lane) <= p) ? m : INFINITY;
    };
    float minv = fminf(comb(w), comb(8 + w));        // jb = w and w+8
    #pragma unroll
    for (int off = 32; off; off >>= 1) minv = fminf(minv, __shfl_down(minv, off));
    if (lane == 0) redm[w] = minv;
    __syncthreads();
    if (tid == 0) {
        float sol = redm[0];
        #pragma unroll
        for (int u = 1; u < 8; ++u) sol = fminf(sol, redm[u]);
        float rank = tval - sol;
        lossw[r] = fmaxf(0.0f, (float)(N - K + 1) - rank);
    }
}

// ===================== K3: deterministic mean ===============================
__global__ __launch_bounds__(64) void k3_loss(
    const float* __restrict__ lossw, float* __restrict__ out, int nrows)
{
    int t = threadIdx.x;
    float loss = (t < nrows) ? lossw[t] : 0.0f;      // kernel-boundary visible
    #pragma unroll
    for (int off = 32; off; off >>= 1) loss += __shfl_down(loss, off);
    if (t == 0) out[0] = loss / (float)nrows;        // /64 = pow2, exact
}

// ===================== fallback: monolithic (R4) ============================
__global__ __launch_bounds__(NTH1) void topk_loss_mono(
    const float* __restrict__ mat, const int* __restrict__ target,
    float* __restrict__ d_out, int nrows)
{
    __shared__ float S[1025];
    __shared__ float rcp[N];
    __shared__ float sx[1024];
    __shared__ float wtot[8];
    __shared__ float red[8];
    __shared__ int   cnt_sh;

    const int tid  = threadIdx.x;
    const int lane = tid & 63;
    const int w    = tid >> 6;
    const int i0   = (w << 7) + lane;
    const int i1   = i0 + 64;
    const float* row = mat + blockIdx.x * N;
    const int   tgt  = target[blockIdx.x];
    const float tval = row[tgt];

    float r0 = row[i0];
    float r1 = (i1 < N) ? row[i1] : -INFINITY;
    if (tid == 0) cnt_sh = 0;
    rcp[tid] = 1.0f / (float)(tid + 1);
    if (tid + NTH1 < N) rcp[tid + NTH1] = 1.0f / (float)(tid + NTH1 + 1);

    int lc = ((r0 > tval) || (r0 == tval && i0 < tgt))
           + ((r1 > tval) || (r1 == tval && i1 < tgt));
    #pragma unroll
    for (int off = 32; off; off >>= 1) lc += __shfl_down(lc, off);
    __syncthreads();
    if (lane == 0 && lc) atomicAdd(&cnt_sh, lc);

    auto cas_shfl = [&](float& rr, int i, unsigned k, unsigned j) {
        float o = __shfl_xor(rr, (int)j);
        bool lower = ((lane & (int)j) == 0);
        bool desc  = ((i & (int)k) == 0);
        rr = (lower == desc) ? fmaxf(rr, o) : fminf(rr, o);
    };
    #pragma unroll
    for (unsigned k = 2; k <= 64; k <<= 1)
        #pragma unroll
        for (unsigned j = k >> 1; j; j >>= 1) { cas_shfl(r0, i0, k, j); cas_shfl(r1, i1, k, j); }
    #pragma unroll
    for (unsigned k = 128; k <= 1024; k <<= 1) {
        #pragma unroll
        for (unsigned j = k >> 1; j >= 128; j >>= 1) {
            __syncthreads();
            sx[i0] = r0; sx[i1] = r1;
            __syncthreads();
            float o0 = sx[i0 ^ (int)j], o1 = sx[i1 ^ (int)j];
            bool lower = ((i0 & (int)j) == 0);
            bool desc  = ((i0 & (int)k) == 0);
            r0 = (lower == desc) ? fmaxf(r0, o0) : fminf(r0, o0);
            r1 = (lower == desc) ? fmaxf(r1, o1) : fminf(r1, o1);
        }
        {
            bool desc = ((i0 & (int)k) == 0);
            float a = fmaxf(r0, r1), b = fminf(r0, r1);
            r0 = desc ? a : b;
            r1 = desc ? b : a;
        }
        #pragma unroll
        for (unsigned j = 32; j; j >>= 1) { cas_shfl(r0, i0, k, j); cas_shfl(r1, i1, k, j); }
    }

    if (i1 >= N) r1 = 0.0f;
    float incl0 = r0;
    #pragma unroll
    for (int off = 1; off < 64; off <<= 1) {
        float y = __shfl_up(incl0, off);
        if (lane >= off) incl0 += y;
    }
    float tot0 = __shfl(incl0, 63);
    float incl1 = r1;
    #pragma unroll
    for (int off = 1; off < 64; off <<= 1) {
        float y = __shfl_up(incl1, off);
        if (lane >= off) incl1 += y;
    }
    if (lane == 63) wtot[w] = incl0 + incl1;
    __syncthreads();
    float base = 0.0f;
    #pragma unroll
    for (int u = 0; u < 8; ++u) { float t = wtot[u]; if (u < w) base += t; }
    if (tid == 0) S[0] = 0.0f;
    S[i0 + 1] = base + incl0;
    S[i1 + 1] = base + tot0 + incl1;
    __syncthreads();

    const int p   = cnt_sh;
    const int len = N - p;
    float minv = INFINITY;
    for (int j = tid; j <= p; j += NTH1) {
        const float  Sj = S[j];
        const float* Sp = &S[p + 1];
        const float* rp = &rcp[p - j];
        const float  cj = 0.5f * (float)(j + p) - (float)N;
        float maxv = -INFINITY;
        #pragma unroll 8
        for (int it = 0; it < len; ++it) {
            float mm = fmaf(Sp[it] - Sj, rp[it], cj + 0.5f * (float)it);
            maxv = fmaxf(maxv, mm);
        }
        minv = fminf(minv, maxv);
    }
    #pragma unroll
    for (int off = 32; off; off >>= 1) minv = fminf(minv, __shfl_down(minv, off));
    if (lane == 0) red[w] = minv;
    __syncthreads();
    if (tid == 0) {
        float sol = red[0];
        #pragma unroll
        for (int u = 1; u < 8; ++u) sol = fminf(sol, red[u]);
        float rank_label = tval - sol;
        float loss = fmaxf(0.0f, (float)(N - 5 + 1) - rank_label);
        atomicAdd(d_out, loss / (float)nrows);
    }
}

extern "C" void kernel_launch(void* const* d_in, const int* in_sizes, int n_in,
                              void* d_out, int out_size, void* d_ws, size_t ws_size,
                              hipStream_t stream) {
    (void)n_in;
    const float* mat    = (const float*)d_in[0];
    const int*   target = (const int*)d_in[1];
    float*       out    = (float*)d_out;
    const int    nrows  = in_sizes[1];   // 64

    if (nrows == 64 && ws_size >= 64 * sizeof(float)) {
        float* lossw = (float*)d_ws;
        k1_fused<<<nrows, NTH1, 0, stream>>>(mat, target, lossw);
        k3_loss<<<1, 64, 0, stream>>>(lossw, out, nrows);
    } else {
        hipMemsetAsync(out, 0, sizeof(float) * out_size, stream);
        topk_loss_mono<<<nrows, NTH1, 0, stream>>>(mat, target, out, nrows);
    }
}

// Round 3
// 67.438 us; speedup vs baseline: 1.1729x; 1.0791x over previous
//
#include <hip/hip_runtime.h>
#include <math.h>

#define N      1000           // NCLASSES
#define NTH1   512            // K1: 8 waves; wave w owns positions [128w,128w+128)
#define NTH2   512            // K2: 64 j-lanes x 8 k-octants (R11: was 256x4)
#define MSLICE 16             // K2 blocks per row
#define SROW   1008           // ws row stride (floats); S[0..1000] only (guarded)
#define META   (64 * SROW)    // float offset of metadata
// meta: [META+r] int p | [META+64+r] tval | [META+128+r] unsigned mr
// R11 ledger: R0 3-dispatch=69.3 (68.0 prev session); R9 fused ticket tail=79.1;
// R10 full fusion (64-block minmax)=72.8. Structure verdict: 3 dispatches win --
// dispatch gaps are cheaper than concentrating the O(p*len) minmax onto 64 CUs,
// and in-kernel completion protocols cost ~+10us. This is R0 with K2 widened to
// 512 threads / 8 k-octants (halves busy-block per-thread iterations; fmax
// regrouping is exact so bitwise-identical output).

// ---- order-preserving float<->uint for atomicMin ----
__device__ inline unsigned fkey(float x) {
    unsigned u = __float_as_uint(x);
    return (u & 0x80000000u) ? ~u : (u | 0x80000000u);
}
__device__ inline float fdecode(unsigned u) {
    return __uint_as_float((u & 0x80000000u) ? (u & 0x7FFFFFFFu) : ~u);
}

// ===================== K1: sort + prefix-scan + rank ========================
__global__ __launch_bounds__(NTH1) void k1_sort_scan(
    const float* __restrict__ mat, const int* __restrict__ target,
    float* __restrict__ ws)
{
    __shared__ float sx[2][1024];    // double-buffered exchange: 1 barrier/stage
    __shared__ float wtot[8];
    __shared__ int   cnt_sh;

    const int tid  = threadIdx.x;
    const int lane = tid & 63;
    const int w    = tid >> 6;
    const int i0   = (w << 7) + lane;
    const int i1   = i0 + 64;
    const int r    = blockIdx.x;
    const float* row = mat + r * N;
    const int   tgt  = target[r];
    const float tval = row[tgt];

    float r0 = row[i0];                          // i0 <= 959 < N
    float r1 = (i1 < N) ? row[i1] : -INFINITY;
    if (tid == 0) cnt_sh = 0;

    // stable descending-sort position of the target
    int lc = ((r0 > tval) || (r0 == tval && i0 < tgt))
           + ((r1 > tval) || (r1 == tval && i1 < tgt));
    #pragma unroll
    for (int off = 32; off; off >>= 1) lc += __shfl_down(lc, off);
    __syncthreads();                             // cnt_sh=0 visible
    if (lane == 0 && lc) atomicAdd(&cnt_sh, lc);

    // bitonic sort, descending (shuffle j<=32, register j=64, LDS j>=128)
    auto cas_shfl = [&](float& rr, int i, unsigned k, unsigned j) {
        float o = __shfl_xor(rr, (int)j);
        bool lower = ((lane & (int)j) == 0);
        bool desc  = ((i & (int)k) == 0);
        rr = (lower == desc) ? fmaxf(rr, o) : fminf(rr, o);
    };
    #pragma unroll
    for (unsigned k = 2; k <= 64; k <<= 1)
        #pragma unroll
        for (unsigned j = k >> 1; j; j >>= 1) { cas_shfl(r0, i0, k, j); cas_shfl(r1, i1, k, j); }
    int buf = 0;
    #pragma unroll
    for (unsigned k = 128; k <= 1024; k <<= 1) {
        #pragma unroll
        for (unsigned j = k >> 1; j >= 128; j >>= 1) {
            // double-buffer: stage-s reads of buf retire (lgkmcnt in barrier)
            // before any wave passes stage-(s+1)'s barrier to rewrite it
            sx[buf][i0] = r0; sx[buf][i1] = r1;
            __syncthreads();
            float o0 = sx[buf][i0 ^ (int)j], o1 = sx[buf][i1 ^ (int)j];
            buf ^= 1;
            bool lower = ((i0 & (int)j) == 0);   // same for i1 (j>=128)
            bool desc  = ((i0 & (int)k) == 0);   // same for i1 (k>=256)
            r0 = (lower == desc) ? fmaxf(r0, o0) : fminf(r0, o0);
            r1 = (lower == desc) ? fmaxf(r1, o1) : fminf(r1, o1);
        }
        {   // j == 64: in-lane register swap
            bool desc = ((i0 & (int)k) == 0);
            float a = fmaxf(r0, r1), b = fminf(r0, r1);
            r0 = desc ? a : b;
            r1 = desc ? b : a;
        }
        #pragma unroll
        for (unsigned j = 32; j; j >>= 1) { cas_shfl(r0, i0, k, j); cas_shfl(r1, i1, k, j); }
    }

    // prefix sums (shuffle scans); -inf pads -> 0
    if (i1 >= N) r1 = 0.0f;
    float incl0 = r0;
    #pragma unroll
    for (int off = 1; off < 64; off <<= 1) {
        float y = __shfl_up(incl0, off);
        if (lane >= off) incl0 += y;
    }
    float tot0 = __shfl(incl0, 63);
    float incl1 = r1;
    #pragma unroll
    for (int off = 1; off < 64; off <<= 1) {
        float y = __shfl_up(incl1, off);
        if (lane >= off) incl1 += y;
    }
    if (lane == 63) wtot[w] = incl0 + incl1;
    __syncthreads();
    float base = 0.0f;
    #pragma unroll
    for (int u = 0; u < 8; ++u) { float t = wtot[u]; if (u < w) base += t; }

    float* Sg = ws + r * SROW;
    if (tid == 0) Sg[0] = 0.0f;
    Sg[i0 + 1] = base + incl0;                   // i0+1 <= 960 < SROW
    if (i1 < N) Sg[i1 + 1] = base + tot0 + incl1;   // only S[1..1000]
    if (tid == 0) {
        ((int*)ws)[META + r]            = cnt_sh;        // p
        ws[META + 64 + r]               = tval;
        ((unsigned*)ws)[META + 128 + r] = 0xFFFFFFFFu;   // mr sentinel (+max key)
    }
}

// ===================== K2: min-max at position p ============================
__global__ __launch_bounds__(NTH2) void k2_minmax(
    const float* __restrict__ ws, unsigned* __restrict__ mr)
{
    __shared__ float Sloc[N];    // S[p+1 .. N]
    __shared__ float rtab[N];    // 1/(d+1)
    __shared__ float maxh[NTH2];

    const int r  = blockIdx.y;
    const int m  = blockIdx.x;
    const int t  = threadIdx.x;
    const int p  = ((const int*)ws)[META + r];
    const int j0 = m * 64;
    if (j0 > p) return;                        // idle slices exit immediately
    const int len = N - p;
    const float* Srow = ws + r * SROW;

    const int jl = t & 63;
    const int j  = j0 + jl;
    const float Sj = (j <= p) ? Srow[j] : 0.0f;   // hoisted global load

    for (int i = t; i < len; i += NTH2) Sloc[i] = Srow[p + 1 + i];
    for (int d = t; d < N; d += NTH2) rtab[d] = 1.0f / (float)(d + 1);
    __syncthreads();

    const int q  = t >> 6;                 // wave-uniform k-octant (0..7)
    const int k0 = (q * len) >> 3;
    const int k1 = ((q + 1) * len) >> 3;
    float maxv = -INFINITY;
    if (j <= p) {
        const float* sp = &Sloc[k0];       // wave-uniform addr -> broadcast
        const float* rp = &rtab[p + k0 - j];  // stride-1 across lanes
        float c = 0.5f * (float)(j + p + k0) - (float)N;  // (j+k)/2 - N
        #pragma unroll 8
        for (int it = 0; it < k1 - k0; ++it) {
            float mval = fmaf(sp[it] - Sj, rp[it], c);
            maxv = fmaxf(maxv, mval);
            c += 0.5f;                     // exact (multiples of 0.5)
        }
    }
    maxh[t] = maxv;
    __syncthreads();
    if (t < 64) {                          // combine octants + min-reduce
        float mv = maxh[t];
        #pragma unroll
        for (int o = 1; o < 8; ++o) mv = fmaxf(mv, maxh[t + (o << 6)]);
        float minv = (j0 + t <= p) ? mv : INFINITY;
        #pragma unroll
        for (int off = 32; off; off >>= 1)
            minv = fminf(minv, __shfl_down(minv, off));
        if (t == 0) atomicMin(&mr[r], fkey(minv));
    }
}

// ===================== K3: loss + mean ======================================
__global__ __launch_bounds__(64) void k3_loss(
    const unsigned* __restrict__ mr, const float* __restrict__ tv,
    float* __restrict__ out, int nrows)
{
    int t = threadIdx.x;
    float loss = 0.0f;
    if (t < nrows) {
        float sol  = fdecode(mr[t]);
        float rank = tv[t] - sol;
        loss = fmaxf(0.0f, (float)(N - 5 + 1) - rank);
    }
    #pragma unroll
    for (int off = 32; off; off >>= 1) loss += __shfl_down(loss, off);
    if (t == 0) out[0] = loss / (float)nrows;
}

// ===================== fallback: monolithic (R4) ============================
__global__ __launch_bounds__(NTH1) void topk_loss_mono(
    const float* __restrict__ mat, const int* __restrict__ target,
    float* __restrict__ d_out, int nrows)
{
    __shared__ float S[1025];
    __shared__ float rcp[N];
    __shared__ float sx[1024];
    __shared__ float wtot[8];
    __shared__ float red[8];
    __shared__ int   cnt_sh;

    const int tid  = threadIdx.x;
    const int lane = tid & 63;
    const int w    = tid >> 6;
    const int i0   = (w << 7) + lane;
    const int i1   = i0 + 64;
    const float* row = mat + blockIdx.x * N;
    const int   tgt  = target[blockIdx.x];
    const float tval = row[tgt];

    float r0 = row[i0];
    float r1 = (i1 < N) ? row[i1] : -INFINITY;
    if (tid == 0) cnt_sh = 0;
    rcp[tid] = 1.0f / (float)(tid + 1);
    if (tid + NTH1 < N) rcp[tid + NTH1] = 1.0f / (float)(tid + NTH1 + 1);

    int lc = ((r0 > tval) || (r0 == tval && i0 < tgt))
           + ((r1 > tval) || (r1 == tval && i1 < tgt));
    #pragma unroll
    for (int off = 32; off; off >>= 1) lc += __shfl_down(lc, off);
    __syncthreads();
    if (lane == 0 && lc) atomicAdd(&cnt_sh, lc);

    auto cas_shfl = [&](float& rr, int i, unsigned k, unsigned j) {
        float o = __shfl_xor(rr, (int)j);
        bool lower = ((lane & (int)j) == 0);
        bool desc  = ((i & (int)k) == 0);
        rr = (lower == desc) ? fmaxf(rr, o) : fminf(rr, o);
    };
    #pragma unroll
    for (unsigned k = 2; k <= 64; k <<= 1)
        #pragma unroll
        for (unsigned j = k >> 1; j; j >>= 1) { cas_shfl(r0, i0, k, j); cas_shfl(r1, i1, k, j); }
    #pragma unroll
    for (unsigned k = 128; k <= 1024; k <<= 1) {
        #pragma unroll
        for (unsigned j = k >> 1; j >= 128; j >>= 1) {
            __syncthreads();
            sx[i0] = r0; sx[i1] = r1;
            __syncthreads();
            float o0 = sx[i0 ^ (int)j], o1 = sx[i1 ^ (int)j];
            bool lower = ((i0 & (int)j) == 0);
            bool desc  = ((i0 & (int)k) == 0);
            r0 = (lower == desc) ? fmaxf(r0, o0) : fminf(r0, o0);
            r1 = (lower == desc) ? fmaxf(r1, o1) : fminf(r1, o1);
        }
        {
            bool desc = ((i0 & (int)k) == 0);
            float a = fmaxf(r0, r1), b = fminf(r0, r1);
            r0 = desc ? a : b;
            r1 = desc ? b : a;
        }
        #pragma unroll
        for (unsigned j = 32; j; j >>= 1) { cas_shfl(r0, i0, k, j); cas_shfl(r1, i1, k, j); }
    }

    if (i1 >= N) r1 = 0.0f;
    float incl0 = r0;
    #pragma unroll
    for (int off = 1; off < 64; off <<= 1) {
        float y = __shfl_up(incl0, off);
        if (lane >= off) incl0 += y;
    }
    float tot0 = __shfl(incl0, 63);
    float incl1 = r1;
    #pragma unroll
    for (int off = 1; off < 64; off <<= 1) {
        float y = __shfl_up(incl1, off);
        if (lane >= off) incl1 += y;
    }
    if (lane == 63) wtot[w] = incl0 + incl1;
    __syncthreads();
    float base = 0.0f;
    #pragma unroll
    for (int u = 0; u < 8; ++u) { float t = wtot[u]; if (u < w) base += t; }
    if (tid == 0) S[0] = 0.0f;
    S[i0 + 1] = base + incl0;
    S[i1 + 1] = base + tot0 + incl1;
    __syncthreads();

    const int p   = cnt_sh;
    const int len = N - p;
    float minv = INFINITY;
    for (int j = tid; j <= p; j += NTH1) {
        const float  Sj = S[j];
        const float* Sp = &S[p + 1];
        const float* rp = &rcp[p - j];
        const float  cj = 0.5f * (float)(j + p) - (float)N;
        float maxv = -INFINITY;
        #pragma unroll 8
        for (int it = 0; it < len; ++it) {
            float mm = fmaf(Sp[it] - Sj, rp[it], cj + 0.5f * (float)it);
            maxv = fmaxf(maxv, mm);
        }
        minv = fminf(minv, maxv);
    }
    #pragma unroll
    for (int off = 32; off; off >>= 1) minv = fminf(minv, __shfl_down(minv, off));
    if (lane == 0) red[w] = minv;
    __syncthreads();
    if (tid == 0) {
        float sol = red[0];
        #pragma unroll
        for (int u = 1; u < 8; ++u) sol = fminf(sol, red[u]);
        float rank_label = tval - sol;
        float loss = fmaxf(0.0f, (float)(N - 5 + 1) - rank_label);
        atomicAdd(d_out, loss / (float)nrows);
    }
}

extern "C" void kernel_launch(void* const* d_in, const int* in_sizes, int n_in,
                              void* d_out, int out_size, void* d_ws, size_t ws_size,
                              hipStream_t stream) {
    (void)n_in;
    const float* mat    = (const float*)d_in[0];
    const int*   target = (const int*)d_in[1];
    float*       out    = (float*)d_out;
    const int    nrows  = in_sizes[1];   // 64

    const size_t need = (size_t)(META + 256) * sizeof(float);
    if (nrows == 64 && ws_size >= need) {
        float*    ws = (float*)d_ws;
        float*    tv = ws + META + 64;
        unsigned* mr = (unsigned*)(ws + META + 128);
        k1_sort_scan<<<nrows, NTH1, 0, stream>>>(mat, target, ws);
        dim3 g2(MSLICE, nrows);
        k2_minmax<<<g2, NTH2, 0, stream>>>(ws, mr);
        k3_loss<<<1, 64, 0, stream>>>(mr, tv, out, nrows);
    } else {
        hipMemsetAsync(out, 0, sizeof(float) * out_size, stream);
        topk_loss_mono<<<nrows, NTH1, 0, stream>>>(mat, target, out, nrows);
    }
}